// Round 8
// baseline (366.589 us; speedup 1.0000x reference)
//
#include <hip/hip_runtime.h>

typedef unsigned short u16;
typedef __attribute__((ext_vector_type(4))) float f32x4;
typedef __attribute__((ext_vector_type(8))) _Float16 f16x8;
typedef __attribute__((ext_vector_type(8))) unsigned short u16x8;
typedef __attribute__((ext_vector_type(4))) unsigned short u16x4;

#define DEV __device__ __forceinline__

// ---------- helpers ----------
DEV u16 f2h(float f) {
    _Float16 h = (_Float16)f;
    u16 r;
    __builtin_memcpy(&r, &h, 2);
    return r;
}
DEV float h2f(u16 u) {
    _Float16 h;
    __builtin_memcpy(&h, &u, 2);
    return (float)h;
}

DEV f32x4 mfma16(f16x8 a, f16x8 b, f32x4 c) {
    return __builtin_amdgcn_mfma_f32_16x16x32_f16(a, b, c, 0, 0, 0);
}

DEV void gload16(const void* g, void* l) {
    __builtin_amdgcn_global_load_lds(
        (const __attribute__((address_space(1))) void*)g,
        (__attribute__((address_space(3))) void*)l, 16, 0, 0);
}

// ---------- problem constants ----------
#define BB 4
#define NN 4096
#define CC 512
#define CI 256
#define RR (BB * NN)  // 16384

// ---------- workspace layout (bytes) ----------
#define OFF_FEAT 0u                     // 16 MB: feat; reused for attn partial O splits 4,5
#define OFF_Q    16777216u
#define OFF_K    25165824u
#define OFF_V    33554432u              // V^T layout [b][d][key], keys sigma-permuted per 32
#define OFF_Y    41943040u
#define OFF_WQKV 50331648u              // 768KB; reused for attn m/l (exactly 768KB)
#define OFF_WO   51118080u
#define OFF_BQKV 51380224u
#define OFF_PART 51383296u              // 512KB: bn partials
#define OFF_SS   51907584u

// ============ BN stats ============
__global__ void bn_partial(const float* __restrict__ x, float* __restrict__ part) {
    const int c = threadIdx.x;
    const int blk = blockIdx.x;
    const float* xp = x + (size_t)blk * 128 * CC + c;
    float s = 0.f, q = 0.f;
    for (int r = 0; r < 128; r++) {
        float v = xp[(size_t)r * CC];
        s += v; q += v * v;
    }
    part[blk * 1024 + c] = s;
    part[blk * 1024 + 512 + c] = q;
}

__global__ void bn_final(const float* __restrict__ part,
                         const float* __restrict__ gamma, const float* __restrict__ beta,
                         float* __restrict__ ss) {
    const int c = threadIdx.x;
    float s = 0.f, q = 0.f;
    for (int i = 0; i < 128; i++) {
        s += part[i * 1024 + c];
        q += part[i * 1024 + 512 + c];
    }
    float m = s * (1.0f / (float)RR);
    float var = q * (1.0f / (float)RR) - m * m;
    float istd = rsqrtf(var + 1e-5f);
    float g = gamma[c] * istd;
    ss[c] = g;
    ss[512 + c] = beta[c] - m * g;
}

// ============ weight conversion ============
__global__ void cvt_weights(const float* __restrict__ thw, const float* __restrict__ phw,
                            const float* __restrict__ gw,
                            const float* __restrict__ thb, const float* __restrict__ phb,
                            const float* __restrict__ gb,
                            const float* __restrict__ ww,
                            u16* __restrict__ wqkv, u16* __restrict__ wo,
                            float* __restrict__ bqkv) {
    const int idx = blockIdx.x * 256 + threadIdx.x;
    if (idx < 768 * 512) {
        int row = idx >> 9, col = idx & 511;
        float v = (row < 256) ? thw[row * 512 + col]
                : (row < 512) ? phw[(row - 256) * 512 + col]
                              : gw[(row - 512) * 512 + col];
        wqkv[idx] = f2h(v);
    } else if (idx < 768 * 512 + 512 * 256) {
        int j = idx - 768 * 512;
        wo[j] = f2h(ww[j]);
    }
    if (idx < 768) {
        bqkv[idx] = (idx < 256) ? thb[idx] : (idx < 512) ? phb[idx - 256] : gb[idx - 512];
    }
}

// ============ BN apply + ReLU -> fp16 ============
__global__ void feat_kernel(const float* __restrict__ x, const float* __restrict__ ss,
                            u16* __restrict__ feat) {
    const int total = RR * CC / 4;
    for (int idx = blockIdx.x * blockDim.x + threadIdx.x; idx < total;
         idx += gridDim.x * blockDim.x) {
        f32x4 xv = ((const f32x4*)x)[idx];
        int c4 = idx & 127;
        f32x4 sc = ((const f32x4*)ss)[c4];
        f32x4 sh = ((const f32x4*)(ss + 512))[c4];
        u16x4 o;
        #pragma unroll
        for (int e = 0; e < 4; e++) {
            float f = fmaxf(xv[e] * sc[e] + sh[e], 0.f);
            o[e] = f2h(f);
        }
        ((u16x4*)feat)[idx] = o;
    }
}

// ============ GEMM ============
// MODE 0: Q,K row-major [token][d]; V TRANSPOSED [b][d][key] with keys
//         sigma-permuted within each 32-block (PV A-fragments lane-local).
// MODE 1: out = x + A*B^T + bias -> fp32 (N=512)
template <int MODE>
__global__ __launch_bounds__(256) void gemm_bt(
    const u16* __restrict__ A, const u16* __restrict__ Bm, int K,
    const float* __restrict__ bias, const float* __restrict__ xres,
    u16* __restrict__ oq, u16* __restrict__ okk, u16* __restrict__ ov,
    float* __restrict__ of) {
    __shared__ u16 As[128 * 32];
    __shared__ u16 Bs[128 * 32];
    const int tid = threadIdx.x;
    const int lane = tid & 63;
    const int l15 = lane & 15, kg = lane >> 4;
    const int wv = tid >> 6;
    const int wm = wv >> 1, wn = wv & 1;
    const int m0 = blockIdx.x * 128, n0 = blockIdx.y * 128;

    f32x4 acc[4][4];
    #pragma unroll
    for (int i = 0; i < 4; i++)
        #pragma unroll
        for (int j = 0; j < 4; j++) acc[i][j] = (f32x4){0.f, 0.f, 0.f, 0.f};

    const int rowA = tid >> 2, colA = (tid & 3) * 8;
    for (int k0 = 0; k0 < K; k0 += 32) {
        gload16(A + (size_t)(m0 + rowA) * K + k0 + colA, &As[tid * 8]);
        gload16(A + (size_t)(m0 + 64 + rowA) * K + k0 + colA, &As[2048 + tid * 8]);
        gload16(Bm + (size_t)(n0 + rowA) * K + k0 + colA, &Bs[tid * 8]);
        gload16(Bm + (size_t)(n0 + 64 + rowA) * K + k0 + colA, &Bs[2048 + tid * 8]);
        __syncthreads();
        f16x8 af[4], bfr[4];
        #pragma unroll
        for (int i = 0; i < 4; i++)
            af[i] = *(const f16x8*)&As[(wm * 64 + i * 16 + l15) * 32 + kg * 8];
        #pragma unroll
        for (int i = 0; i < 4; i++)
            bfr[i] = *(const f16x8*)&Bs[(wn * 64 + i * 16 + l15) * 32 + kg * 8];
        #pragma unroll
        for (int mi = 0; mi < 4; mi++)
            #pragma unroll
            for (int ni = 0; ni < 4; ni++)
                acc[mi][ni] = mfma16(af[mi], bfr[ni], acc[mi][ni]);
        __syncthreads();
    }

    #pragma unroll
    for (int mi = 0; mi < 4; mi++) {
        #pragma unroll
        for (int ni = 0; ni < 4; ni++) {
            #pragma unroll
            for (int r = 0; r < 4; r++) {
                int row = m0 + wm * 64 + mi * 16 + kg * 4 + r;
                int col = n0 + wn * 64 + ni * 16 + l15;
                float v = acc[mi][ni][r];
                if constexpr (MODE == 0) {
                    v += bias[col];
                    u16 hv = f2h(v);
                    if (n0 < 256) {
                        oq[(size_t)row * CI + col] = hv;
                    } else if (n0 < 512) {
                        okk[(size_t)row * CI + (col - 256)] = hv;
                    } else {
                        int d = col - 512;
                        int bi = row >> 12, key = row & (NN - 1);
                        int k5 = key & 31;
                        int skey = (key & ~31) |
                                   ((((k5 >> 2) & 3) << 3) | (k5 & 3) | (((k5 >> 4) & 1) << 2));
                        ov[((size_t)bi * CI + d) * NN + skey] = hv;  // V^T, sigma-permuted
                    }
                } else {
                    size_t o = (size_t)row * 512 + col;
                    of[o] = xres[o] + v + bias[col];
                }
            }
        }
    }
}

// ============ flash attention, swapped-QK^T, split-KV x6 ============
// grid 768 = 4 batches x 32 q-tiles(128 rows) x 6 key-splits; block 256 = 4 waves x 32 q-rows
// LDS: Ks [32][256] swz single (16KB) | Vt 2x[256][32] swz dbuf (32KB) = 49152 B -> 3 blocks/CU
#define KVB 32
#define NSPLIT 6
#define ATTN_LDS 49152

DEV void stageK32(const u16* __restrict__ Kg, size_t kvbase, int kv0, u16* Ks, int tid) {
    const int chunk = tid & 31, rb = tid >> 5;
    #pragma unroll
    for (int i = 0; i < 4; i++) {
        int row = i * 8 + rb;
        int sc = chunk ^ (row & 7);
        gload16(Kg + kvbase + (size_t)(kv0 + row) * CI + sc * 8,
                &Ks[row * 256 + chunk * 8]);
    }
}

DEV void stageV32(const u16* __restrict__ Vtg, size_t vbase, int kv0, u16* Vt, int tid) {
    const int c = tid & 3, db = tid >> 2;
    #pragma unroll
    for (int i = 0; i < 4; i++) {
        int d = i * 64 + db;
        int sc = c ^ ((d >> 1) & 3);
        gload16(Vtg + vbase + (size_t)d * NN + kv0 + sc * 8,
                &Vt[d * KVB + c * 8]);
    }
}

__global__ __launch_bounds__(256, 3) void attn_kernel(
    const u16* __restrict__ Qg, const u16* __restrict__ Kg,
    const u16* __restrict__ Vtg, u16* __restrict__ poA, u16* __restrict__ poB,
    float* __restrict__ ml) {
    extern __shared__ u16 smem[];

    const int tid = threadIdx.x, lane = tid & 63, wv = tid >> 6;
    const int l15 = lane & 15, kg = lane >> 4;
    // XCD-aware swizzle (768 = 8 x 96)
    const int sid = (blockIdx.x & 7) * 96 + (blockIdx.x >> 3);
    const int qt = sid & 31;
    const int b = (sid >> 5) & 3;
    const int sp = sid >> 7;             // key split 0..5
    const int k0 = ((sp * 64) / 3) * 32;             // 32-aligned split start
    const int k1 = (((sp + 1) * 64) / 3) * 32;
    const int ntile = (k1 - k0) >> 5;                // 21 or 22
    const size_t kvbase = (size_t)b * NN * CI;
    const size_t vbase = (size_t)b * CI * NN;

    // Q as B-fragments: lane holds Q rows (l15, l15+16), d-slice kg*8+j at step kk
    f16x8 qf[2][8];
    {
        const u16* qp0 = Qg + ((size_t)b * NN + qt * 128 + wv * 32 + l15) * CI + kg * 8;
        #pragma unroll
        for (int qs = 0; qs < 2; qs++)
            #pragma unroll
            for (int kk = 0; kk < 8; kk++)
                qf[qs][kk] = *(const f16x8*)(qp0 + (size_t)qs * 16 * CI + kk * 32);
    }

    // acc: O[q][d], col d = dt*16+l15, row q = qs*16 + kg*4 + r
    f32x4 acc[16][2];
    #pragma unroll
    for (int i = 0; i < 16; i++)
        #pragma unroll
        for (int qs = 0; qs < 2; qs++) acc[i][qs] = (f32x4){0.f, 0.f, 0.f, 0.f};
    float mrow[2] = {-1e30f, -1e30f}, lrow[2] = {0.f, 0.f};

    u16* Ks = smem;                      // single-buffered K (16KB)
    // V double buffer at smem+8192 (elems), each 8192 elems

    stageK32(Kg, kvbase, k0, Ks, tid);
    stageV32(Vtg, vbase, k0, smem + 8192, tid);
    __syncthreads();

    for (int it = 0; it < ntile; ++it) {
        const u16* Vt = smem + 8192 + (it & 1) * 8192;
        // prefetch next V into alternate buffer (free until next iter's PV)
        if (it + 1 < ntile)
            stageV32(Vtg, vbase, k0 + (it + 1) * KVB, smem + 8192 + (((it + 1) & 1) * 8192), tid);

        // ---- S^T = K Q^T : lane holds S[key = nt*16+kg*4+r][q = l15+16qs]
        f32x4 s[2][2];
        #pragma unroll
        for (int qs = 0; qs < 2; qs++)
            #pragma unroll
            for (int nt = 0; nt < 2; nt++) s[qs][nt] = (f32x4){0.f, 0.f, 0.f, 0.f};
        __builtin_amdgcn_s_setprio(1);
        #pragma unroll
        for (int kk = 0; kk < 8; kk++) {
            #pragma unroll
            for (int nt = 0; nt < 2; nt++) {
                int krow = nt * 16 + l15;
                f16x8 kf = *(const f16x8*)&Ks[krow * 256 + (((kk * 4 + kg) ^ (krow & 7)) << 3)];
                s[0][nt] = mfma16(kf, qf[0][kk], s[0][nt]);
                s[1][nt] = mfma16(kf, qf[1][kk], s[1][nt]);
            }
        }
        __builtin_amdgcn_s_setprio(0);

        __syncthreads();   // barrier1: all waves done reading Ks (V(it+1) also drained)
        // reload K into the single buffer; covered by softmax+PV below
        if (it + 1 < ntile)
            stageK32(Kg, kvbase, k0 + (it + 1) * KVB, Ks, tid);

        // ---- softmax, lane-local rows (q = l15+16qs) + 2-shfl cross-kg reduce
        float mx[2];
        #pragma unroll
        for (int qs = 0; qs < 2; qs++) {
            float m8 = fmaxf(fmaxf(fmaxf(s[qs][0][0], s[qs][0][1]), fmaxf(s[qs][0][2], s[qs][0][3])),
                             fmaxf(fmaxf(s[qs][1][0], s[qs][1][1]), fmaxf(s[qs][1][2], s[qs][1][3])));
            m8 = fmaxf(m8, __shfl_xor(m8, 16));
            m8 = fmaxf(m8, __shfl_xor(m8, 32));
            mx[qs] = m8;
        }
        float need = fmaxf(mx[0] - mrow[0], mx[1] - mrow[1]);
        if (!__all(need <= 8.f)) {   // defer-max: rescale only when needed
            float sclv[2];
            #pragma unroll
            for (int qs = 0; qs < 2; qs++) {
                float mnew = fmaxf(mrow[qs], mx[qs]);
                sclv[qs] = __expf(mrow[qs] - mnew);
                lrow[qs] *= sclv[qs];
                mrow[qs] = mnew;
            }
            #pragma unroll
            for (int qs = 0; qs < 2; qs++)
                #pragma unroll
                for (int r = 0; r < 4; r++) {
                    float sr = __shfl(sclv[qs], (lane & 48) | (kg * 4 + r), 64);
                    #pragma unroll
                    for (int dt = 0; dt < 16; dt++) acc[dt][qs][r] *= sr;
                }
        }
        // exp + row-sum + pack P to fp16 A-fragment (keys at mfma-k = kg*8 + nt*4 + r)
        f16x8 pa[2];
        #pragma unroll
        for (int qs = 0; qs < 2; qs++) {
            float rs = 0.f;
            #pragma unroll
            for (int nt = 0; nt < 2; nt++)
                #pragma unroll
                for (int r = 0; r < 4; r++) {
                    float p = __expf(s[qs][nt][r] - mrow[qs]);
                    rs += p;
                    pa[qs][nt * 4 + r] = (_Float16)p;
                }
            rs += __shfl_xor(rs, 16);
            rs += __shfl_xor(rs, 32);
            lrow[qs] += rs;
        }

        // ---- PV: O[q][d] += P(32q x 32k) * V(32k x 256d)
        __builtin_amdgcn_s_setprio(1);
        #pragma unroll
        for (int dt = 0; dt < 16; dt++) {
            int d = dt * 16 + l15;
            f16x8 vf = *(const f16x8*)&Vt[d * KVB + ((kg ^ ((l15 >> 1) & 3)) << 3)];
            acc[dt][0] = mfma16(pa[0], vf, acc[dt][0]);
            acc[dt][1] = mfma16(pa[1], vf, acc[dt][1]);
        }
        __builtin_amdgcn_s_setprio(0);

        __syncthreads();   // barrier2: Vt readers done; K(it+1)/V(it+1) drained
    }

    // ---- write normalized partial O (fp16) + m/l
    const int row0 = b * NN + qt * 128 + wv * 32;
    u16* pod = (sp < 4) ? (poA + (size_t)sp * RR * CI)
                        : (poB + (size_t)(sp - 4) * RR * CI);
    #pragma unroll
    for (int qs = 0; qs < 2; qs++)
        #pragma unroll
        for (int r = 0; r < 4; r++) {
            float li = __shfl(lrow[qs], (lane & 48) | (kg * 4 + r), 64);
            float inv = 1.f / li;
            int row = row0 + qs * 16 + kg * 4 + r;
            #pragma unroll
            for (int dt = 0; dt < 16; dt++)
                pod[(size_t)row * CI + dt * 16 + l15] = f2h(acc[dt][qs][r] * inv);
        }
    if (kg == 0) {
        #pragma unroll
        for (int qs = 0; qs < 2; qs++) {
            int row = row0 + qs * 16 + l15;
            ml[row * 12 + sp * 2] = mrow[qs];
            ml[row * 12 + sp * 2 + 1] = lrow[qs];
        }
    }
}

// ============ combine the six KV-splits ============
__global__ void attn_combine(const u16* __restrict__ poA, const u16* __restrict__ poB,
                             const float* __restrict__ ml, u16* __restrict__ yb) {
    const int gid = blockIdx.x * 256 + threadIdx.x;  // RR*CI/4 threads
    const int row = gid >> 6;
    const int d0 = (gid & 63) * 4;
    f32x4 ml0 = ((const f32x4*)ml)[row * 3];
    f32x4 ml1 = ((const f32x4*)ml)[row * 3 + 1];
    f32x4 ml2 = ((const f32x4*)ml)[row * 3 + 2];
    float m = fmaxf(fmaxf(fmaxf(ml0[0], ml0[2]), fmaxf(ml1[0], ml1[2])),
                    fmaxf(ml2[0], ml2[2]));
    float c0 = __expf(ml0[0] - m) * ml0[1];
    float c1 = __expf(ml0[2] - m) * ml0[3];
    float c2 = __expf(ml1[0] - m) * ml1[1];
    float c3 = __expf(ml1[2] - m) * ml1[3];
    float c4 = __expf(ml2[0] - m) * ml2[1];
    float c5 = __expf(ml2[2] - m) * ml2[3];
    float inv = 1.f / (c0 + c1 + c2 + c3 + c4 + c5);
    const size_t off = (size_t)row * CI + d0;
    const size_t spstride = (size_t)RR * CI;
    u16x4 p0 = *(const u16x4*)(poA + off);
    u16x4 p1 = *(const u16x4*)(poA + spstride + off);
    u16x4 p2 = *(const u16x4*)(poA + 2 * spstride + off);
    u16x4 p3 = *(const u16x4*)(poA + 3 * spstride + off);
    u16x4 p4 = *(const u16x4*)(poB + off);
    u16x4 p5 = *(const u16x4*)(poB + spstride + off);
    u16x4 o;
    #pragma unroll
    for (int e = 0; e < 4; e++)
        o[e] = f2h((c0 * h2f(p0[e]) + c1 * h2f(p1[e]) + c2 * h2f(p2[e]) +
                    c3 * h2f(p3[e]) + c4 * h2f(p4[e]) + c5 * h2f(p5[e])) * inv);
    *(u16x4*)(yb + off) = o;
}

// ============ launcher ============
extern "C" void kernel_launch(void* const* d_in, const int* in_sizes, int n_in,
                              void* d_out, int out_size, void* d_ws, size_t ws_size,
                              hipStream_t stream) {
    (void)in_sizes; (void)n_in; (void)out_size; (void)ws_size;
    const float* x     = (const float*)d_in[0];
    const float* gamma = (const float*)d_in[1];
    const float* beta  = (const float*)d_in[2];
    const float* thw   = (const float*)d_in[3];
    const float* thb   = (const float*)d_in[4];
    const float* phw   = (const float*)d_in[5];
    const float* phb   = (const float*)d_in[6];
    const float* gw    = (const float*)d_in[7];
    const float* gb    = (const float*)d_in[8];
    const float* ww    = (const float*)d_in[9];
    const float* wb    = (const float*)d_in[10];

    char* ws = (char*)d_ws;
    u16* feat  = (u16*)(ws + OFF_FEAT);   // reused: attn partial O splits 4,5 (16MB)
    u16* qb    = (u16*)(ws + OFF_Q);
    u16* kb    = (u16*)(ws + OFF_K);
    u16* vtb   = (u16*)(ws + OFF_V);
    u16* yb    = (u16*)(ws + OFF_Y);
    u16* wqkv  = (u16*)(ws + OFF_WQKV);   // reused: attn m/l (768KB exactly)
    u16* wo    = (u16*)(ws + OFF_WO);
    float* bqkv = (float*)(ws + OFF_BQKV);
    float* part = (float*)(ws + OFF_PART);
    float* ss   = (float*)(ws + OFF_SS);
    float* out  = (float*)d_out;
    u16* poA   = (u16*)d_out;             // scratch: 32MB of d_out = splits 0..3
    float* mlp = (float*)(ws + OFF_WQKV); // m/l after gemm0 consumed wqkv

    (void)hipFuncSetAttribute((const void*)attn_kernel,
                              hipFuncAttributeMaxDynamicSharedMemorySize, ATTN_LDS);

    bn_partial<<<128, 512, 0, stream>>>(x, part);
    bn_final<<<1, 512, 0, stream>>>(part, gamma, beta, ss);
    cvt_weights<<<2048, 256, 0, stream>>>(thw, phw, gw, thb, phb, gb, ww, wqkv, wo, bqkv);
    feat_kernel<<<2048, 256, 0, stream>>>(x, ss, feat);
    gemm_bt<0><<<dim3(128, 6), 256, 0, stream>>>(feat, wqkv, 512, bqkv, nullptr,
                                                 qb, kb, vtb, nullptr);
    attn_kernel<<<768, 256, ATTN_LDS, stream>>>(qb, kb, vtb, poA, feat, mlp);
    attn_combine<<<RR * CI / 4 / 256, 256, 0, stream>>>(poA, feat, mlp, yb);
    gemm_bt<1><<<dim3(128, 4), 256, 0, stream>>>(yb, wo, 256, wb, x,
                                                 nullptr, nullptr, nullptr, out);
}

// Round 9
// 175.893 us; speedup vs baseline: 2.0842x; 2.0842x over previous
//
#include <hip/hip_runtime.h>

typedef unsigned short u16;
typedef __attribute__((ext_vector_type(4))) float f32x4;
typedef __attribute__((ext_vector_type(8))) _Float16 f16x8;
typedef __attribute__((ext_vector_type(8))) unsigned short u16x8;
typedef __attribute__((ext_vector_type(4))) unsigned short u16x4;

#define DEV __device__ __forceinline__

// ---------- helpers ----------
DEV u16 f2h(float f) {
    _Float16 h = (_Float16)f;
    u16 r;
    __builtin_memcpy(&r, &h, 2);
    return r;
}
DEV float h2f(u16 u) {
    _Float16 h;
    __builtin_memcpy(&h, &u, 2);
    return (float)h;
}

DEV f32x4 mfma16(f16x8 a, f16x8 b, f32x4 c) {
    return __builtin_amdgcn_mfma_f32_16x16x32_f16(a, b, c, 0, 0, 0);
}

DEV void gload16(const void* g, void* l) {
    __builtin_amdgcn_global_load_lds(
        (const __attribute__((address_space(1))) void*)g,
        (__attribute__((address_space(3))) void*)l, 16, 0, 0);
}

// ---------- problem constants ----------
#define BB 4
#define NN 4096
#define CC 512
#define CI 256
#define RR (BB * NN)  // 16384

// ---------- workspace layout (bytes) ----------
#define OFF_FEAT 0u                     // 16 MB: feat; reused for attn partial O split 2
#define OFF_Q    16777216u
#define OFF_K    25165824u
#define OFF_V    33554432u              // V^T layout [b][d][key], keys sigma-permuted per 32
#define OFF_Y    41943040u
#define OFF_WQKV 50331648u              // 768KB; reused for attn m/l (384KB needed)
#define OFF_WO   51118080u
#define OFF_BQKV 51380224u
#define OFF_PART 51383296u              // 512KB: bn partials
#define OFF_SS   51907584u

// ============ BN stats ============
__global__ void bn_partial(const float* __restrict__ x, float* __restrict__ part) {
    const int c = threadIdx.x;
    const int blk = blockIdx.x;
    const float* xp = x + (size_t)blk * 128 * CC + c;
    float s = 0.f, q = 0.f;
    for (int r = 0; r < 128; r++) {
        float v = xp[(size_t)r * CC];
        s += v; q += v * v;
    }
    part[blk * 1024 + c] = s;
    part[blk * 1024 + 512 + c] = q;
}

// ============ merged: bn_final (block 1024) + weight cvt (blocks 0..1023) ============
__global__ void prep_kernel(const float* __restrict__ part,
                            const float* __restrict__ gamma, const float* __restrict__ beta,
                            float* __restrict__ ss,
                            const float* __restrict__ thw, const float* __restrict__ phw,
                            const float* __restrict__ gw,
                            const float* __restrict__ thb, const float* __restrict__ phb,
                            const float* __restrict__ gb,
                            const float* __restrict__ ww,
                            u16* __restrict__ wqkv, u16* __restrict__ wo,
                            float* __restrict__ bqkv) {
    if (blockIdx.x == 1024) {
        const int c = threadIdx.x;  // 512 threads
        float s = 0.f, q = 0.f;
        for (int i = 0; i < 128; i++) {
            s += part[i * 1024 + c];
            q += part[i * 1024 + 512 + c];
        }
        float m = s * (1.0f / (float)RR);
        float var = q * (1.0f / (float)RR) - m * m;
        float istd = rsqrtf(var + 1e-5f);
        float g = gamma[c] * istd;
        ss[c] = g;
        ss[512 + c] = beta[c] - m * g;
        return;
    }
    const int idx = blockIdx.x * 512 + threadIdx.x;  // 0..524287
    if (idx < 768 * 512) {
        int row = idx >> 9, col = idx & 511;
        float v = (row < 256) ? thw[row * 512 + col]
                : (row < 512) ? phw[(row - 256) * 512 + col]
                              : gw[(row - 512) * 512 + col];
        wqkv[idx] = f2h(v);
    } else {
        int j = idx - 768 * 512;  // < 512*256
        wo[j] = f2h(ww[j]);
    }
    if (idx < 768) {
        bqkv[idx] = (idx < 256) ? thb[idx] : (idx < 512) ? phb[idx - 256] : gb[idx - 512];
    }
}

// ============ BN apply + ReLU -> fp16 ============
__global__ void feat_kernel(const float* __restrict__ x, const float* __restrict__ ss,
                            u16* __restrict__ feat) {
    const int total = RR * CC / 4;
    for (int idx = blockIdx.x * blockDim.x + threadIdx.x; idx < total;
         idx += gridDim.x * blockDim.x) {
        f32x4 xv = ((const f32x4*)x)[idx];
        int c4 = idx & 127;
        f32x4 sc = ((const f32x4*)ss)[c4];
        f32x4 sh = ((const f32x4*)(ss + 512))[c4];
        u16x4 o;
        #pragma unroll
        for (int e = 0; e < 4; e++) {
            float f = fmaxf(xv[e] * sc[e] + sh[e], 0.f);
            o[e] = f2h(f);
        }
        ((u16x4*)feat)[idx] = o;
    }
}

// ============ GEMM ============
// MODE 0: Q,K row-major [token][d]; V TRANSPOSED [b][d][key] with keys
//         sigma-permuted within each 32-block (PV A-fragments lane-local).
// MODE 1: out = x + A*B^T + bias -> fp32 (N=512)
template <int MODE>
__global__ __launch_bounds__(256) void gemm_bt(
    const u16* __restrict__ A, const u16* __restrict__ Bm, int K,
    const float* __restrict__ bias, const float* __restrict__ xres,
    u16* __restrict__ oq, u16* __restrict__ okk, u16* __restrict__ ov,
    float* __restrict__ of) {
    __shared__ u16 As[128 * 32];
    __shared__ u16 Bs[128 * 32];
    const int tid = threadIdx.x;
    const int lane = tid & 63;
    const int l15 = lane & 15, kg = lane >> 4;
    const int wv = tid >> 6;
    const int wm = wv >> 1, wn = wv & 1;
    const int m0 = blockIdx.x * 128, n0 = blockIdx.y * 128;

    f32x4 acc[4][4];
    #pragma unroll
    for (int i = 0; i < 4; i++)
        #pragma unroll
        for (int j = 0; j < 4; j++) acc[i][j] = (f32x4){0.f, 0.f, 0.f, 0.f};

    const int rowA = tid >> 2, colA = (tid & 3) * 8;
    for (int k0 = 0; k0 < K; k0 += 32) {
        gload16(A + (size_t)(m0 + rowA) * K + k0 + colA, &As[tid * 8]);
        gload16(A + (size_t)(m0 + 64 + rowA) * K + k0 + colA, &As[2048 + tid * 8]);
        gload16(Bm + (size_t)(n0 + rowA) * K + k0 + colA, &Bs[tid * 8]);
        gload16(Bm + (size_t)(n0 + 64 + rowA) * K + k0 + colA, &Bs[2048 + tid * 8]);
        __syncthreads();
        f16x8 af[4], bfr[4];
        #pragma unroll
        for (int i = 0; i < 4; i++)
            af[i] = *(const f16x8*)&As[(wm * 64 + i * 16 + l15) * 32 + kg * 8];
        #pragma unroll
        for (int i = 0; i < 4; i++)
            bfr[i] = *(const f16x8*)&Bs[(wn * 64 + i * 16 + l15) * 32 + kg * 8];
        #pragma unroll
        for (int mi = 0; mi < 4; mi++)
            #pragma unroll
            for (int ni = 0; ni < 4; ni++)
                acc[mi][ni] = mfma16(af[mi], bfr[ni], acc[mi][ni]);
        __syncthreads();
    }

    #pragma unroll
    for (int mi = 0; mi < 4; mi++) {
        #pragma unroll
        for (int ni = 0; ni < 4; ni++) {
            #pragma unroll
            for (int r = 0; r < 4; r++) {
                int row = m0 + wm * 64 + mi * 16 + kg * 4 + r;
                int col = n0 + wn * 64 + ni * 16 + l15;
                float v = acc[mi][ni][r];
                if constexpr (MODE == 0) {
                    v += bias[col];
                    u16 hv = f2h(v);
                    if (n0 < 256) {
                        oq[(size_t)row * CI + col] = hv;
                    } else if (n0 < 512) {
                        okk[(size_t)row * CI + (col - 256)] = hv;
                    } else {
                        int d = col - 512;
                        int bi = row >> 12, key = row & (NN - 1);
                        int k5 = key & 31;
                        int skey = (key & ~31) |
                                   ((((k5 >> 2) & 3) << 3) | (k5 & 3) | (((k5 >> 4) & 1) << 2));
                        ov[((size_t)bi * CI + d) * NN + skey] = hv;  // V^T, sigma-permuted
                    }
                } else {
                    size_t o = (size_t)row * 512 + col;
                    of[o] = xres[o] + v + bias[col];
                }
            }
        }
    }
}

// ============ flash attention, swapped-QK^T, 16 q-rows/wave, split-KV x3 ============
// grid 768 = 4 batches x 64 q-tiles(64 rows) x 3 key-splits; block 256 = 4 waves x 16 q-rows
// LDS: Ks [32][256] swz single (16KB) | Vt 2x[256][32] swz dbuf (32KB) = 49152 -> 3 blocks/CU
// Per-wave regs ~140 total (acc 64 + qf 32 + s 8 + misc) -> fits (256,3) cap without spill.
#define KVB 32
#define NSPLIT 3
#define ATTN_LDS 49152

DEV void stageK32(const u16* __restrict__ Kg, size_t kvbase, int kv0, u16* Ks, int tid) {
    const int chunk = tid & 31, rb = tid >> 5;
    #pragma unroll
    for (int i = 0; i < 4; i++) {
        int row = i * 8 + rb;
        int sc = chunk ^ (row & 7);
        gload16(Kg + kvbase + (size_t)(kv0 + row) * CI + sc * 8,
                &Ks[row * 256 + chunk * 8]);
    }
}

DEV void stageV32(const u16* __restrict__ Vtg, size_t vbase, int kv0, u16* Vt, int tid) {
    const int c = tid & 3, db = tid >> 2;
    #pragma unroll
    for (int i = 0; i < 4; i++) {
        int d = i * 64 + db;
        int sc = c ^ ((d >> 1) & 3);
        gload16(Vtg + vbase + (size_t)d * NN + kv0 + sc * 8,
                &Vt[d * KVB + c * 8]);
    }
}

__global__ __launch_bounds__(256, 3) void attn_kernel(
    const u16* __restrict__ Qg, const u16* __restrict__ Kg,
    const u16* __restrict__ Vtg, u16* __restrict__ poA, u16* __restrict__ poB,
    float* __restrict__ ml) {
    extern __shared__ u16 smem[];

    const int tid = threadIdx.x, lane = tid & 63, wv = tid >> 6;
    const int l15 = lane & 15, kg = lane >> 4;
    // XCD-aware swizzle (768 = 8 x 96)
    const int sid = (blockIdx.x & 7) * 96 + (blockIdx.x >> 3);
    const int qt = sid & 63;
    const int b = (sid >> 6) & 3;
    const int sp = sid >> 8;                         // key split 0..2
    const int k0 = ((sp * 128) / 3) * 32;            // 32-aligned split bounds
    const int k1 = (((sp + 1) * 128) / 3) * 32;
    const int ntile = (k1 - k0) >> 5;                // 42 or 43
    const size_t kvbase = (size_t)b * NN * CI;
    const size_t vbase = (size_t)b * CI * NN;

    // Q as B-fragments: lane holds Q row l15 of this wave's 16-row stripe,
    // d-slice kg*8+j at step kk.
    f16x8 qf[8];
    {
        const u16* qp0 = Qg + ((size_t)b * NN + qt * 64 + wv * 16 + l15) * CI + kg * 8;
        #pragma unroll
        for (int kk = 0; kk < 8; kk++) qf[kk] = *(const f16x8*)(qp0 + kk * 32);
    }

    // acc: O[q][d], col d = dt*16+l15, row q = kg*4 + r
    f32x4 acc[16];
    #pragma unroll
    for (int i = 0; i < 16; i++) acc[i] = (f32x4){0.f, 0.f, 0.f, 0.f};
    float mrow = -1e30f, lrow = 0.f;

    u16* Ks = smem;                      // single-buffered K (16KB)
    // V double buffer at smem+8192 (elems), each 8192 elems (32KB)

    stageK32(Kg, kvbase, k0, Ks, tid);
    stageV32(Vtg, vbase, k0, smem + 8192, tid);
    __syncthreads();

    for (int it = 0; it < ntile; ++it) {
        const u16* Vt = smem + 8192 + (it & 1) * 8192;
        // prefetch next V into alternate buffer
        if (it + 1 < ntile)
            stageV32(Vtg, vbase, k0 + (it + 1) * KVB, smem + 8192 + (((it + 1) & 1) * 8192), tid);

        // ---- S^T = K Q^T : lane holds S[key = nt*16+kg*4+r][q = l15]
        f32x4 s[2];
        #pragma unroll
        for (int nt = 0; nt < 2; nt++) s[nt] = (f32x4){0.f, 0.f, 0.f, 0.f};
        __builtin_amdgcn_s_setprio(1);
        #pragma unroll
        for (int kk = 0; kk < 8; kk++) {
            #pragma unroll
            for (int nt = 0; nt < 2; nt++) {
                int krow = nt * 16 + l15;
                f16x8 kf = *(const f16x8*)&Ks[krow * 256 + (((kk * 4 + kg) ^ (krow & 7)) << 3)];
                s[nt] = mfma16(kf, qf[kk], s[nt]);
            }
        }
        __builtin_amdgcn_s_setprio(0);

        __syncthreads();   // barrier1: all waves done reading Ks (V prefetch also drained)
        // reload K into the single buffer; covered by softmax+PV below
        if (it + 1 < ntile)
            stageK32(Kg, kvbase, k0 + (it + 1) * KVB, Ks, tid);

        // ---- softmax, lane-local row q = l15, 2-shfl cross-kg reduce
        float mx = fmaxf(fmaxf(fmaxf(s[0][0], s[0][1]), fmaxf(s[0][2], s[0][3])),
                         fmaxf(fmaxf(s[1][0], s[1][1]), fmaxf(s[1][2], s[1][3])));
        mx = fmaxf(mx, __shfl_xor(mx, 16));
        mx = fmaxf(mx, __shfl_xor(mx, 32));
        if (!__all(mx - mrow <= 8.f)) {   // defer-max: rescale only when needed
            float mnew = fmaxf(mrow, mx);
            float scl = __expf(mrow - mnew);
            lrow *= scl;
            mrow = mnew;
            #pragma unroll
            for (int r = 0; r < 4; r++) {
                float sr = __shfl(scl, (lane & 48) | (kg * 4 + r), 64);
                #pragma unroll
                for (int dt = 0; dt < 16; dt++) acc[dt][r] *= sr;
            }
        }
        // exp + row-sum + pack P to fp16 A-fragment (keys at mfma-k = kg*8 + nt*4 + r)
        f16x8 pa;
        float rs = 0.f;
        #pragma unroll
        for (int nt = 0; nt < 2; nt++)
            #pragma unroll
            for (int r = 0; r < 4; r++) {
                float p = __expf(s[nt][r] - mrow);
                rs += p;
                pa[nt * 4 + r] = (_Float16)p;
            }
        rs += __shfl_xor(rs, 16);
        rs += __shfl_xor(rs, 32);
        lrow += rs;

        // ---- PV: O[q][d] += P(16q x 32k) * V(32k x 256d)
        __builtin_amdgcn_s_setprio(1);
        #pragma unroll
        for (int dt = 0; dt < 16; dt++) {
            int d = dt * 16 + l15;
            f16x8 vf = *(const f16x8*)&Vt[d * KVB + ((kg ^ ((l15 >> 1) & 3)) << 3)];
            acc[dt] = mfma16(pa, vf, acc[dt]);
        }
        __builtin_amdgcn_s_setprio(0);

        __syncthreads();   // barrier2: Vt readers done; K(it+1)/V(it+1) drained
    }

    // ---- write normalized partial O (fp16) + m/l
    const int row0 = b * NN + qt * 64 + wv * 16;
    u16* pod = (sp < 2) ? (poA + (size_t)sp * RR * CI) : poB;
    #pragma unroll
    for (int r = 0; r < 4; r++) {
        float li = __shfl(lrow, (lane & 48) | (kg * 4 + r), 64);
        float inv = 1.f / li;
        int row = row0 + kg * 4 + r;
        #pragma unroll
        for (int dt = 0; dt < 16; dt++)
            pod[(size_t)row * CI + dt * 16 + l15] = f2h(acc[dt][r] * inv);
    }
    if (kg == 0) {
        int row = row0 + l15;
        ml[row * 6 + sp * 2] = mrow;
        ml[row * 6 + sp * 2 + 1] = lrow;
    }
}

// ============ combine the three KV-splits ============
__global__ void attn_combine(const u16* __restrict__ poA, const u16* __restrict__ poB,
                             const float* __restrict__ ml, u16* __restrict__ yb) {
    const int gid = blockIdx.x * 256 + threadIdx.x;  // RR*CI/4 threads
    const int row = gid >> 6;
    const int d0 = (gid & 63) * 4;
    const float* mlr = ml + row * 6;
    float m0_ = mlr[0], l0 = mlr[1];
    float m1_ = mlr[2], l1 = mlr[3];
    float m2_ = mlr[4], l2 = mlr[5];
    float m = fmaxf(fmaxf(m0_, m1_), m2_);
    float c0 = __expf(m0_ - m) * l0;
    float c1 = __expf(m1_ - m) * l1;
    float c2 = __expf(m2_ - m) * l2;
    float inv = 1.f / (c0 + c1 + c2);
    const size_t off = (size_t)row * CI + d0;
    const size_t spstride = (size_t)RR * CI;
    u16x4 p0 = *(const u16x4*)(poA + off);
    u16x4 p1 = *(const u16x4*)(poA + spstride + off);
    u16x4 p2 = *(const u16x4*)(poB + off);
    u16x4 o;
    #pragma unroll
    for (int e = 0; e < 4; e++)
        o[e] = f2h((c0 * h2f(p0[e]) + c1 * h2f(p1[e]) + c2 * h2f(p2[e])) * inv);
    *(u16x4*)(yb + off) = o;
}

// ============ launcher ============
extern "C" void kernel_launch(void* const* d_in, const int* in_sizes, int n_in,
                              void* d_out, int out_size, void* d_ws, size_t ws_size,
                              hipStream_t stream) {
    (void)in_sizes; (void)n_in; (void)out_size; (void)ws_size;
    const float* x     = (const float*)d_in[0];
    const float* gamma = (const float*)d_in[1];
    const float* beta  = (const float*)d_in[2];
    const float* thw   = (const float*)d_in[3];
    const float* thb   = (const float*)d_in[4];
    const float* phw   = (const float*)d_in[5];
    const float* phb   = (const float*)d_in[6];
    const float* gw    = (const float*)d_in[7];
    const float* gb    = (const float*)d_in[8];
    const float* ww    = (const float*)d_in[9];
    const float* wb    = (const float*)d_in[10];

    char* ws = (char*)d_ws;
    u16* feat  = (u16*)(ws + OFF_FEAT);   // reused: attn partial O split 2 (8MB)
    u16* qb    = (u16*)(ws + OFF_Q);
    u16* kb    = (u16*)(ws + OFF_K);
    u16* vtb   = (u16*)(ws + OFF_V);
    u16* yb    = (u16*)(ws + OFF_Y);
    u16* wqkv  = (u16*)(ws + OFF_WQKV);   // reused: attn m/l (384KB)
    u16* wo    = (u16*)(ws + OFF_WO);
    float* bqkv = (float*)(ws + OFF_BQKV);
    float* part = (float*)(ws + OFF_PART);
    float* ss   = (float*)(ws + OFF_SS);
    float* out  = (float*)d_out;
    u16* poA   = (u16*)d_out;             // scratch: 16MB of d_out = splits 0,1
    float* mlp = (float*)(ws + OFF_WQKV); // m/l after gemm0 consumed wqkv

    (void)hipFuncSetAttribute((const void*)attn_kernel,
                              hipFuncAttributeMaxDynamicSharedMemorySize, ATTN_LDS);

    bn_partial<<<128, 512, 0, stream>>>(x, part);
    prep_kernel<<<1025, 512, 0, stream>>>(part, gamma, beta, ss,
                                          thw, phw, gw, thb, phb, gb, ww, wqkv, wo, bqkv);
    feat_kernel<<<2048, 256, 0, stream>>>(x, ss, feat);
    gemm_bt<0><<<dim3(128, 6), 256, 0, stream>>>(feat, wqkv, 512, bqkv, nullptr,
                                                 qb, kb, vtb, nullptr);
    attn_kernel<<<768, 256, ATTN_LDS, stream>>>(qb, kb, vtb, poA, feat, mlp);
    attn_combine<<<RR * CI / 4 / 256, 256, 0, stream>>>(poA, feat, mlp, yb);
    gemm_bt<1><<<dim3(128, 4), 256, 0, stream>>>(yb, wo, 256, wb, x,
                                                 nullptr, nullptr, nullptr, out);
}

// Round 10
// 162.942 us; speedup vs baseline: 2.2498x; 1.0795x over previous
//
#include <hip/hip_runtime.h>

typedef unsigned short u16;
typedef __attribute__((ext_vector_type(4))) float f32x4;
typedef __attribute__((ext_vector_type(8))) _Float16 f16x8;
typedef __attribute__((ext_vector_type(8))) unsigned short u16x8;
typedef __attribute__((ext_vector_type(4))) unsigned short u16x4;

#define DEV __device__ __forceinline__

// ---------- helpers ----------
DEV u16 f2h(float f) {
    _Float16 h = (_Float16)f;
    u16 r;
    __builtin_memcpy(&r, &h, 2);
    return r;
}
DEV float h2f(u16 u) {
    _Float16 h;
    __builtin_memcpy(&h, &u, 2);
    return (float)h;
}

DEV f32x4 mfma16(f16x8 a, f16x8 b, f32x4 c) {
    return __builtin_amdgcn_mfma_f32_16x16x32_f16(a, b, c, 0, 0, 0);
}

DEV void gload16(const void* g, void* l) {
    __builtin_amdgcn_global_load_lds(
        (const __attribute__((address_space(1))) void*)g,
        (__attribute__((address_space(3))) void*)l, 16, 0, 0);
}

// ---------- problem constants ----------
#define BB 4
#define NN 4096
#define CC 512
#define CI 256
#define RR (BB * NN)  // 16384

// ---------- workspace layout (bytes) ----------
#define OFF_FEAT 0u                     // 16 MB: feat; reused for attn partial O splits 0,1
#define OFF_Q    16777216u
#define OFF_K    25165824u
#define OFF_V    33554432u              // V^T layout [b][d][key], keys sigma-permuted per 32
#define OFF_Y    41943040u
#define OFF_WQKV 50331648u
#define OFF_WO   51118080u
#define OFF_BQKV 51380224u
#define OFF_PART 51383296u              // 512KB: bn partials; reused for attn m/l (exactly 512KB)
#define OFF_SS   51907584u

// ============ BN stats ============
__global__ void bn_partial(const float* __restrict__ x, float* __restrict__ part) {
    const int c = threadIdx.x;
    const int blk = blockIdx.x;
    const float* xp = x + (size_t)blk * 128 * CC + c;
    float s = 0.f, q = 0.f;
    for (int r = 0; r < 128; r++) {
        float v = xp[(size_t)r * CC];
        s += v; q += v * v;
    }
    part[blk * 1024 + c] = s;
    part[blk * 1024 + 512 + c] = q;
}

// ============ merged: bn_final (block 1024) + weight cvt (blocks 0..1023) ============
__global__ void prep_kernel(const float* __restrict__ part,
                            const float* __restrict__ gamma, const float* __restrict__ beta,
                            float* __restrict__ ss,
                            const float* __restrict__ thw, const float* __restrict__ phw,
                            const float* __restrict__ gw,
                            const float* __restrict__ thb, const float* __restrict__ phb,
                            const float* __restrict__ gb,
                            const float* __restrict__ ww,
                            u16* __restrict__ wqkv, u16* __restrict__ wo,
                            float* __restrict__ bqkv) {
    if (blockIdx.x == 1024) {
        const int c = threadIdx.x;  // 512 threads
        float s = 0.f, q = 0.f;
        for (int i = 0; i < 128; i++) {
            s += part[i * 1024 + c];
            q += part[i * 1024 + 512 + c];
        }
        float m = s * (1.0f / (float)RR);
        float var = q * (1.0f / (float)RR) - m * m;
        float istd = rsqrtf(var + 1e-5f);
        float g = gamma[c] * istd;
        ss[c] = g;
        ss[512 + c] = beta[c] - m * g;
        return;
    }
    const int idx = blockIdx.x * 512 + threadIdx.x;  // 0..524287
    if (idx < 768 * 512) {
        int row = idx >> 9, col = idx & 511;
        float v = (row < 256) ? thw[row * 512 + col]
                : (row < 512) ? phw[(row - 256) * 512 + col]
                              : gw[(row - 512) * 512 + col];
        wqkv[idx] = f2h(v);
    } else {
        int j = idx - 768 * 512;  // < 512*256
        wo[j] = f2h(ww[j]);
    }
    if (idx < 768) {
        bqkv[idx] = (idx < 256) ? thb[idx] : (idx < 512) ? phb[idx - 256] : gb[idx - 512];
    }
}

// ============ BN apply + ReLU -> fp16 ============
__global__ void feat_kernel(const float* __restrict__ x, const float* __restrict__ ss,
                            u16* __restrict__ feat) {
    const int total = RR * CC / 4;
    for (int idx = blockIdx.x * blockDim.x + threadIdx.x; idx < total;
         idx += gridDim.x * blockDim.x) {
        f32x4 xv = ((const f32x4*)x)[idx];
        int c4 = idx & 127;
        f32x4 sc = ((const f32x4*)ss)[c4];
        f32x4 sh = ((const f32x4*)(ss + 512))[c4];
        u16x4 o;
        #pragma unroll
        for (int e = 0; e < 4; e++) {
            float f = fmaxf(xv[e] * sc[e] + sh[e], 0.f);
            o[e] = f2h(f);
        }
        ((u16x4*)feat)[idx] = o;
    }
}

// ============ GEMM ============
// MODE 0: Q,K row-major [token][d]; V TRANSPOSED [b][d][key] with keys
//         sigma-permuted within each 32-block (PV A-fragments lane-local).
// MODE 1: out = x + A*B^T + bias -> fp32 (N=512)
template <int MODE>
__global__ __launch_bounds__(256) void gemm_bt(
    const u16* __restrict__ A, const u16* __restrict__ Bm, int K,
    const float* __restrict__ bias, const float* __restrict__ xres,
    u16* __restrict__ oq, u16* __restrict__ okk, u16* __restrict__ ov,
    float* __restrict__ of) {
    __shared__ u16 As[128 * 32];
    __shared__ u16 Bs[128 * 32];
    const int tid = threadIdx.x;
    const int lane = tid & 63;
    const int l15 = lane & 15, kg = lane >> 4;
    const int wv = tid >> 6;
    const int wm = wv >> 1, wn = wv & 1;
    const int m0 = blockIdx.x * 128, n0 = blockIdx.y * 128;

    f32x4 acc[4][4];
    #pragma unroll
    for (int i = 0; i < 4; i++)
        #pragma unroll
        for (int j = 0; j < 4; j++) acc[i][j] = (f32x4){0.f, 0.f, 0.f, 0.f};

    const int rowA = tid >> 2, colA = (tid & 3) * 8;
    for (int k0 = 0; k0 < K; k0 += 32) {
        gload16(A + (size_t)(m0 + rowA) * K + k0 + colA, &As[tid * 8]);
        gload16(A + (size_t)(m0 + 64 + rowA) * K + k0 + colA, &As[2048 + tid * 8]);
        gload16(Bm + (size_t)(n0 + rowA) * K + k0 + colA, &Bs[tid * 8]);
        gload16(Bm + (size_t)(n0 + 64 + rowA) * K + k0 + colA, &Bs[2048 + tid * 8]);
        __syncthreads();
        f16x8 af[4], bfr[4];
        #pragma unroll
        for (int i = 0; i < 4; i++)
            af[i] = *(const f16x8*)&As[(wm * 64 + i * 16 + l15) * 32 + kg * 8];
        #pragma unroll
        for (int i = 0; i < 4; i++)
            bfr[i] = *(const f16x8*)&Bs[(wn * 64 + i * 16 + l15) * 32 + kg * 8];
        #pragma unroll
        for (int mi = 0; mi < 4; mi++)
            #pragma unroll
            for (int ni = 0; ni < 4; ni++)
                acc[mi][ni] = mfma16(af[mi], bfr[ni], acc[mi][ni]);
        __syncthreads();
    }

    #pragma unroll
    for (int mi = 0; mi < 4; mi++) {
        #pragma unroll
        for (int ni = 0; ni < 4; ni++) {
            #pragma unroll
            for (int r = 0; r < 4; r++) {
                int row = m0 + wm * 64 + mi * 16 + kg * 4 + r;
                int col = n0 + wn * 64 + ni * 16 + l15;
                float v = acc[mi][ni][r];
                if constexpr (MODE == 0) {
                    v += bias[col];
                    u16 hv = f2h(v);
                    if (n0 < 256) {
                        oq[(size_t)row * CI + col] = hv;
                    } else if (n0 < 512) {
                        okk[(size_t)row * CI + (col - 256)] = hv;
                    } else {
                        int d = col - 512;
                        int bi = row >> 12, key = row & (NN - 1);
                        int k5 = key & 31;
                        int skey = (key & ~31) |
                                   ((((k5 >> 2) & 3) << 3) | (k5 & 3) | (((k5 >> 4) & 1) << 2));
                        ov[((size_t)bi * CI + d) * NN + skey] = hv;  // V^T, sigma-permuted
                    }
                } else {
                    size_t o = (size_t)row * 512 + col;
                    of[o] = xres[o] + v + bias[col];
                }
            }
        }
    }
}

// ============ flash attention, swapped-QK^T, 32 q-rows/wave, split-KV x4 ============
// grid 512 = 4 batches x 32 q-tiles(128 rows) x 4 key-splits; block 256 = 4 waves x 32 q-rows
// LDS: Ks 2x[32][256] swz (32KB dbuf) | Vt 2x[256][32] swz (32KB dbuf) = 65536 B
// Staging source pointers hoisted out of the KV loop (advance by constant stride).
#define KVB 32
#define NSPLIT 4
#define KEYS_PER (NN / NSPLIT)          // 1024
#define NTILE (KEYS_PER / KVB)          // 32
#define ATTN_LDS 65536

__global__ __launch_bounds__(256, 2) void attn_kernel(
    const u16* __restrict__ Qg, const u16* __restrict__ Kg,
    const u16* __restrict__ Vtg, u16* __restrict__ po01, u16* __restrict__ po23,
    float* __restrict__ ml) {
    extern __shared__ u16 smem[];

    const int tid = threadIdx.x, lane = tid & 63, wv = tid >> 6;
    const int l15 = lane & 15, kg = lane >> 4;
    // XCD-aware swizzle (512 % 8 == 0)
    const int sid = (blockIdx.x & 7) * 64 + (blockIdx.x >> 3);
    const int qt = sid & 31;
    const int b = (sid >> 5) & 3;
    const int sp = sid >> 7;             // key split 0..3
    const int kvoff = sp * KEYS_PER;
    const size_t kvbase = (size_t)b * NN * CI;
    const size_t vbase = (size_t)b * CI * NN;

    // Q as B-fragments: lane holds Q rows (l15, l15+16), d-slice kg*8+j at step kk
    f16x8 qf[2][8];
    {
        const u16* qp0 = Qg + ((size_t)b * NN + qt * 128 + wv * 32 + l15) * CI + kg * 8;
        #pragma unroll
        for (int qs = 0; qs < 2; qs++)
            #pragma unroll
            for (int kk = 0; kk < 8; kk++)
                qf[qs][kk] = *(const f16x8*)(qp0 + (size_t)qs * 16 * CI + kk * 32);
    }

    // acc: O[q][d], col d = dt*16+l15, row q = qs*16 + kg*4 + r
    f32x4 acc[16][2];
    #pragma unroll
    for (int i = 0; i < 16; i++)
        #pragma unroll
        for (int qs = 0; qs < 2; qs++) acc[i][qs] = (f32x4){0.f, 0.f, 0.f, 0.f};
    float mrow[2] = {-1e30f, -1e30f}, lrow[2] = {0.f, 0.f};

    // ---- hoisted staging geometry (loop-invariant except +const stride) ----
    const int chunk = tid & 31, rb = tid >> 5;       // K staging
    const u16* ksrc[4];
    int kdst[4];
    #pragma unroll
    for (int i = 0; i < 4; i++) {
        int row = i * 8 + rb;
        int sc = chunk ^ (row & 7);
        ksrc[i] = Kg + kvbase + (size_t)(kvoff + KVB + row) * CI + sc * 8;  // tile 1
        kdst[i] = row * 256 + chunk * 8;
    }
    const int vc = tid & 3, vdb = tid >> 2;          // V staging
    const u16* vsrc[4];
    int vdst[4];
    #pragma unroll
    for (int i = 0; i < 4; i++) {
        int d = i * 64 + vdb;
        int sc = vc ^ ((d >> 1) & 3);
        vsrc[i] = Vtg + vbase + (size_t)d * NN + kvoff + KVB + sc * 8;     // tile 1
        vdst[i] = d * KVB + vc * 8;
    }

    // prologue: stage tile 0 into buffer 0
    #pragma unroll
    for (int i = 0; i < 4; i++) {
        int row = i * 8 + rb;
        int sc = chunk ^ (row & 7);
        gload16(Kg + kvbase + (size_t)(kvoff + row) * CI + sc * 8, smem + kdst[i]);
    }
    #pragma unroll
    for (int i = 0; i < 4; i++) {
        int d = i * 64 + vdb;
        int sc = vc ^ ((d >> 1) & 3);
        gload16(Vtg + vbase + (size_t)d * NN + kvoff + sc * 8, smem + 16384 + vdst[i]);
    }
    __syncthreads();

    for (int it = 0; it < NTILE; ++it) {
        const int cur = (it & 1) * 8192;
        const u16* Ks = smem + cur;
        const u16* Vt = smem + 16384 + cur;
        // prefetch next tile into the other buffer (pointers pre-advanced)
        if (it + 1 < NTILE) {
            const int nxt = cur ^ 8192;
            #pragma unroll
            for (int i = 0; i < 4; i++) {
                gload16(ksrc[i], smem + nxt + kdst[i]);
                ksrc[i] += KVB * CI;
            }
            #pragma unroll
            for (int i = 0; i < 4; i++) {
                gload16(vsrc[i], smem + 16384 + nxt + vdst[i]);
                vsrc[i] += KVB;
            }
        }

        // ---- S^T = K Q^T : lane holds S[key = nt*16+kg*4+r][q = l15+16qs]
        f32x4 s[2][2];
        #pragma unroll
        for (int qs = 0; qs < 2; qs++)
            #pragma unroll
            for (int nt = 0; nt < 2; nt++) s[qs][nt] = (f32x4){0.f, 0.f, 0.f, 0.f};
        __builtin_amdgcn_s_setprio(1);
        #pragma unroll
        for (int kk = 0; kk < 8; kk++) {
            #pragma unroll
            for (int nt = 0; nt < 2; nt++) {
                int krow = nt * 16 + l15;
                f16x8 kf = *(const f16x8*)&Ks[krow * 256 + (((kk * 4 + kg) ^ (krow & 7)) << 3)];
                s[0][nt] = mfma16(kf, qf[0][kk], s[0][nt]);
                s[1][nt] = mfma16(kf, qf[1][kk], s[1][nt]);
            }
        }
        __builtin_amdgcn_s_setprio(0);

        // ---- softmax, lane-local rows (q = l15+16qs) + 2-shfl cross-kg reduce
        float mx[2];
        #pragma unroll
        for (int qs = 0; qs < 2; qs++) {
            float m8 = fmaxf(fmaxf(fmaxf(s[qs][0][0], s[qs][0][1]), fmaxf(s[qs][0][2], s[qs][0][3])),
                             fmaxf(fmaxf(s[qs][1][0], s[qs][1][1]), fmaxf(s[qs][1][2], s[qs][1][3])));
            m8 = fmaxf(m8, __shfl_xor(m8, 16));
            m8 = fmaxf(m8, __shfl_xor(m8, 32));
            mx[qs] = m8;
        }
        float need = fmaxf(mx[0] - mrow[0], mx[1] - mrow[1]);
        if (!__all(need <= 8.f)) {   // defer-max: rescale only when needed
            float sclv[2];
            #pragma unroll
            for (int qs = 0; qs < 2; qs++) {
                float mnew = fmaxf(mrow[qs], mx[qs]);
                sclv[qs] = __expf(mrow[qs] - mnew);
                lrow[qs] *= sclv[qs];
                mrow[qs] = mnew;
            }
            #pragma unroll
            for (int qs = 0; qs < 2; qs++)
                #pragma unroll
                for (int r = 0; r < 4; r++) {
                    float sr = __shfl(sclv[qs], (lane & 48) | (kg * 4 + r), 64);
                    #pragma unroll
                    for (int dt = 0; dt < 16; dt++) acc[dt][qs][r] *= sr;
                }
        }
        // exp + row-sum + pack P to fp16 A-fragment (keys at mfma-k = kg*8 + nt*4 + r)
        f16x8 pa[2];
        #pragma unroll
        for (int qs = 0; qs < 2; qs++) {
            float rs = 0.f;
            #pragma unroll
            for (int nt = 0; nt < 2; nt++)
                #pragma unroll
                for (int r = 0; r < 4; r++) {
                    float p = __expf(s[qs][nt][r] - mrow[qs]);
                    rs += p;
                    pa[qs][nt * 4 + r] = (_Float16)p;
                }
            rs += __shfl_xor(rs, 16);
            rs += __shfl_xor(rs, 32);
            lrow[qs] += rs;
        }

        // ---- PV: O[q][d] += P(32q x 32k) * V(32k x 256d)
        __builtin_amdgcn_s_setprio(1);
        #pragma unroll
        for (int dt = 0; dt < 16; dt++) {
            int d = dt * 16 + l15;
            f16x8 vf = *(const f16x8*)&Vt[d * KVB + ((kg ^ ((l15 >> 1) & 3)) << 3)];
            acc[dt][0] = mfma16(pa[0], vf, acc[dt][0]);
            acc[dt][1] = mfma16(pa[1], vf, acc[dt][1]);
        }
        __builtin_amdgcn_s_setprio(0);

        __syncthreads();  // waves done with cur buffers; prefetch drained
    }

    // ---- write normalized partial O (fp16) + m/l
    const int row0 = b * NN + qt * 128 + wv * 32;
    u16* pod = (sp < 2) ? (po01 + (size_t)sp * RR * CI)
                        : (po23 + (size_t)(sp - 2) * RR * CI);
    #pragma unroll
    for (int qs = 0; qs < 2; qs++)
        #pragma unroll
        for (int r = 0; r < 4; r++) {
            float li = __shfl(lrow[qs], (lane & 48) | (kg * 4 + r), 64);
            float inv = 1.f / li;
            int row = row0 + qs * 16 + kg * 4 + r;
            #pragma unroll
            for (int dt = 0; dt < 16; dt++)
                pod[(size_t)row * CI + dt * 16 + l15] = f2h(acc[dt][qs][r] * inv);
        }
    if (kg == 0) {
        #pragma unroll
        for (int qs = 0; qs < 2; qs++) {
            int row = row0 + qs * 16 + l15;
            ml[row * 8 + sp * 2] = mrow[qs];
            ml[row * 8 + sp * 2 + 1] = lrow[qs];
        }
    }
}

// ============ combine the four KV-splits ============
__global__ void attn_combine(const u16* __restrict__ po01, const u16* __restrict__ po23,
                             const float* __restrict__ ml, u16* __restrict__ yb) {
    const int gid = blockIdx.x * 256 + threadIdx.x;  // RR*CI/4 threads
    const int row = gid >> 6;
    const int d0 = (gid & 63) * 4;
    f32x4 ml0 = ((const f32x4*)ml)[row * 2];
    f32x4 ml1 = ((const f32x4*)ml)[row * 2 + 1];
    float m = fmaxf(fmaxf(ml0[0], ml0[2]), fmaxf(ml1[0], ml1[2]));
    float c0 = __expf(ml0[0] - m) * ml0[1];
    float c1 = __expf(ml0[2] - m) * ml0[3];
    float c2 = __expf(ml1[0] - m) * ml1[1];
    float c3 = __expf(ml1[2] - m) * ml1[3];
    float inv = 1.f / (c0 + c1 + c2 + c3);
    const size_t off = (size_t)row * CI + d0;
    const size_t spstride = (size_t)RR * CI;
    u16x4 p0 = *(const u16x4*)(po01 + off);
    u16x4 p1 = *(const u16x4*)(po01 + spstride + off);
    u16x4 p2 = *(const u16x4*)(po23 + off);
    u16x4 p3 = *(const u16x4*)(po23 + spstride + off);
    u16x4 o;
    #pragma unroll
    for (int e = 0; e < 4; e++)
        o[e] = f2h((c0 * h2f(p0[e]) + c1 * h2f(p1[e]) +
                    c2 * h2f(p2[e]) + c3 * h2f(p3[e])) * inv);
    *(u16x4*)(yb + off) = o;
}

// ============ launcher ============
extern "C" void kernel_launch(void* const* d_in, const int* in_sizes, int n_in,
                              void* d_out, int out_size, void* d_ws, size_t ws_size,
                              hipStream_t stream) {
    (void)in_sizes; (void)n_in; (void)out_size; (void)ws_size;
    const float* x     = (const float*)d_in[0];
    const float* gamma = (const float*)d_in[1];
    const float* beta  = (const float*)d_in[2];
    const float* thw   = (const float*)d_in[3];
    const float* thb   = (const float*)d_in[4];
    const float* phw   = (const float*)d_in[5];
    const float* phb   = (const float*)d_in[6];
    const float* gw    = (const float*)d_in[7];
    const float* gb    = (const float*)d_in[8];
    const float* ww    = (const float*)d_in[9];
    const float* wb    = (const float*)d_in[10];

    char* ws = (char*)d_ws;
    u16* feat  = (u16*)(ws + OFF_FEAT);   // reused: attn partial O splits 0,1 (16MB)
    u16* qb    = (u16*)(ws + OFF_Q);
    u16* kb    = (u16*)(ws + OFF_K);
    u16* vtb   = (u16*)(ws + OFF_V);
    u16* yb    = (u16*)(ws + OFF_Y);
    u16* wqkv  = (u16*)(ws + OFF_WQKV);
    u16* wo    = (u16*)(ws + OFF_WO);
    float* bqkv = (float*)(ws + OFF_BQKV);
    float* part = (float*)(ws + OFF_PART); // reused: attn m/l (512KB exactly)
    float* ss   = (float*)(ws + OFF_SS);
    float* out  = (float*)d_out;
    u16* po23  = (u16*)d_out;             // scratch: first 16MB of d_out = splits 2,3

    (void)hipFuncSetAttribute((const void*)attn_kernel,
                              hipFuncAttributeMaxDynamicSharedMemorySize, ATTN_LDS);

    bn_partial<<<128, 512, 0, stream>>>(x, part);
    prep_kernel<<<1025, 512, 0, stream>>>(part, gamma, beta, ss,
                                          thw, phw, gw, thb, phb, gb, ww, wqkv, wo, bqkv);
    feat_kernel<<<2048, 256, 0, stream>>>(x, ss, feat);
    gemm_bt<0><<<dim3(128, 6), 256, 0, stream>>>(feat, wqkv, 512, bqkv, nullptr,
                                                 qb, kb, vtb, nullptr);
    attn_kernel<<<512, 256, ATTN_LDS, stream>>>(qb, kb, vtb, feat, po23, part);
    attn_combine<<<RR * CI / 4 / 256, 256, 0, stream>>>(feat, po23, part, yb);
    gemm_bt<1><<<dim3(128, 4), 256, 0, stream>>>(yb, wo, 256, wb, x,
                                                 nullptr, nullptr, nullptr, out);
}

// Round 11
// 161.975 us; speedup vs baseline: 2.2632x; 1.0060x over previous
//
#include <hip/hip_runtime.h>

typedef unsigned short u16;
typedef __attribute__((ext_vector_type(4))) float f32x4;
typedef __attribute__((ext_vector_type(8))) _Float16 f16x8;
typedef __attribute__((ext_vector_type(8))) unsigned short u16x8;
typedef __attribute__((ext_vector_type(4))) unsigned short u16x4;

#define DEV __device__ __forceinline__

// ---------- helpers ----------
DEV u16 f2h(float f) {
    _Float16 h = (_Float16)f;
    u16 r;
    __builtin_memcpy(&r, &h, 2);
    return r;
}
DEV float h2f(u16 u) {
    _Float16 h;
    __builtin_memcpy(&h, &u, 2);
    return (float)h;
}

DEV f32x4 mfma16(f16x8 a, f16x8 b, f32x4 c) {
    return __builtin_amdgcn_mfma_f32_16x16x32_f16(a, b, c, 0, 0, 0);
}

DEV void gload16(const void* g, void* l) {
    __builtin_amdgcn_global_load_lds(
        (const __attribute__((address_space(1))) void*)g,
        (__attribute__((address_space(3))) void*)l, 16, 0, 0);
}

// ---------- problem constants ----------
#define BB 4
#define NN 4096
#define CC 512
#define CI 256
#define RR (BB * NN)  // 16384

// ---------- workspace layout (bytes) ----------
#define OFF_FEAT 0u                     // 16 MB: attn partial O splits 0,1 (feat kernel removed)
#define OFF_Q    16777216u
#define OFF_K    25165824u
#define OFF_V    33554432u              // V^T layout [b][d][key], keys sigma-permuted per 32
#define OFF_Y    41943040u
#define OFF_WQKV 50331648u
#define OFF_WO   51118080u
#define OFF_BQKV 51380224u
#define OFF_PART 51383296u              // 512KB: bn partials; reused for attn m/l (exactly 512KB)
#define OFF_SS   51907584u

// ============ BN stats ============
__global__ void bn_partial(const float* __restrict__ x, float* __restrict__ part) {
    const int c = threadIdx.x;
    const int blk = blockIdx.x;
    const float* xp = x + (size_t)blk * 128 * CC + c;
    float s = 0.f, q = 0.f;
    for (int r = 0; r < 128; r++) {
        float v = xp[(size_t)r * CC];
        s += v; q += v * v;
    }
    part[blk * 1024 + c] = s;
    part[blk * 1024 + 512 + c] = q;
}

// ============ merged: bn_final (block 1024) + weight cvt (blocks 0..1023) ============
__global__ void prep_kernel(const float* __restrict__ part,
                            const float* __restrict__ gamma, const float* __restrict__ beta,
                            float* __restrict__ ss,
                            const float* __restrict__ thw, const float* __restrict__ phw,
                            const float* __restrict__ gw,
                            const float* __restrict__ thb, const float* __restrict__ phb,
                            const float* __restrict__ gb,
                            const float* __restrict__ ww,
                            u16* __restrict__ wqkv, u16* __restrict__ wo,
                            float* __restrict__ bqkv) {
    if (blockIdx.x == 1024) {
        const int c = threadIdx.x;  // 512 threads
        float s = 0.f, q = 0.f;
        for (int i = 0; i < 128; i++) {
            s += part[i * 1024 + c];
            q += part[i * 1024 + 512 + c];
        }
        float m = s * (1.0f / (float)RR);
        float var = q * (1.0f / (float)RR) - m * m;
        float istd = rsqrtf(var + 1e-5f);
        float g = gamma[c] * istd;
        ss[c] = g;
        ss[512 + c] = beta[c] - m * g;
        return;
    }
    const int idx = blockIdx.x * 512 + threadIdx.x;  // 0..524287
    if (idx < 768 * 512) {
        int row = idx >> 9, col = idx & 511;
        float v = (row < 256) ? thw[row * 512 + col]
                : (row < 512) ? phw[(row - 256) * 512 + col]
                              : gw[(row - 512) * 512 + col];
        wqkv[idx] = f2h(v);
    } else {
        int j = idx - 768 * 512;  // < 512*256
        wo[j] = f2h(ww[j]);
    }
    if (idx < 768) {
        bqkv[idx] = (idx < 256) ? thb[idx] : (idx < 512) ? phb[idx - 256] : gb[idx - 512];
    }
}

// ============ GEMM ============
// MODE 0: A = BN+ReLU(x) computed ON THE FLY (x fp32 + ss scale/shift), B = wqkv.
//         Outputs: Q,K row-major [token][d]; V TRANSPOSED [b][d][key] with keys
//         sigma-permuted within each 32-block (PV A-fragments lane-local).
// MODE 1: A = yb fp16 (gload_lds); out = x + A*B^T + bias -> fp32 (N=512)
template <int MODE>
__global__ __launch_bounds__(256) void gemm_bt(
    const u16* __restrict__ A, const float* __restrict__ X, const float* __restrict__ ss,
    const u16* __restrict__ Bm, int K,
    const float* __restrict__ bias, const float* __restrict__ xres,
    u16* __restrict__ oq, u16* __restrict__ okk, u16* __restrict__ ov,
    float* __restrict__ of) {
    __shared__ u16 As[128 * 32];
    __shared__ u16 Bs[128 * 32];
    const int tid = threadIdx.x;
    const int lane = tid & 63;
    const int l15 = lane & 15, kg = lane >> 4;
    const int wv = tid >> 6;
    const int wm = wv >> 1, wn = wv & 1;
    const int m0 = blockIdx.x * 128, n0 = blockIdx.y * 128;

    f32x4 acc[4][4];
    #pragma unroll
    for (int i = 0; i < 4; i++)
        #pragma unroll
        for (int j = 0; j < 4; j++) acc[i][j] = (f32x4){0.f, 0.f, 0.f, 0.f};

    const int rowA = tid >> 2, colA = (tid & 3) * 8;
    for (int k0 = 0; k0 < K; k0 += 32) {
        if constexpr (MODE == 0) {
            // fused BN+ReLU A-staging from x (fp32)
            const float* xa = X + (size_t)(m0 + rowA) * CC + k0 + colA;
            f32x4 xv0 = *(const f32x4*)(xa);
            f32x4 xv1 = *(const f32x4*)(xa + 4);
            f32x4 xv2 = *(const f32x4*)(xa + (size_t)64 * CC);
            f32x4 xv3 = *(const f32x4*)(xa + (size_t)64 * CC + 4);
            f32x4 sc0 = *(const f32x4*)(ss + k0 + colA);
            f32x4 sc1 = *(const f32x4*)(ss + k0 + colA + 4);
            f32x4 sh0 = *(const f32x4*)(ss + 512 + k0 + colA);
            f32x4 sh1 = *(const f32x4*)(ss + 512 + k0 + colA + 4);
            u16x8 a0, a1;
            #pragma unroll
            for (int e = 0; e < 4; e++) {
                a0[e]     = f2h(fmaxf(xv0[e] * sc0[e] + sh0[e], 0.f));
                a0[4 + e] = f2h(fmaxf(xv1[e] * sc1[e] + sh1[e], 0.f));
                a1[e]     = f2h(fmaxf(xv2[e] * sc0[e] + sh0[e], 0.f));
                a1[4 + e] = f2h(fmaxf(xv3[e] * sc1[e] + sh1[e], 0.f));
            }
            *(u16x8*)&As[tid * 8] = a0;
            *(u16x8*)&As[2048 + tid * 8] = a1;
        } else {
            gload16(A + (size_t)(m0 + rowA) * K + k0 + colA, &As[tid * 8]);
            gload16(A + (size_t)(m0 + 64 + rowA) * K + k0 + colA, &As[2048 + tid * 8]);
        }
        gload16(Bm + (size_t)(n0 + rowA) * K + k0 + colA, &Bs[tid * 8]);
        gload16(Bm + (size_t)(n0 + 64 + rowA) * K + k0 + colA, &Bs[2048 + tid * 8]);
        __syncthreads();
        f16x8 af[4], bfr[4];
        #pragma unroll
        for (int i = 0; i < 4; i++)
            af[i] = *(const f16x8*)&As[(wm * 64 + i * 16 + l15) * 32 + kg * 8];
        #pragma unroll
        for (int i = 0; i < 4; i++)
            bfr[i] = *(const f16x8*)&Bs[(wn * 64 + i * 16 + l15) * 32 + kg * 8];
        #pragma unroll
        for (int mi = 0; mi < 4; mi++)
            #pragma unroll
            for (int ni = 0; ni < 4; ni++)
                acc[mi][ni] = mfma16(af[mi], bfr[ni], acc[mi][ni]);
        __syncthreads();
    }

    #pragma unroll
    for (int mi = 0; mi < 4; mi++) {
        #pragma unroll
        for (int ni = 0; ni < 4; ni++) {
            #pragma unroll
            for (int r = 0; r < 4; r++) {
                int row = m0 + wm * 64 + mi * 16 + kg * 4 + r;
                int col = n0 + wn * 64 + ni * 16 + l15;
                float v = acc[mi][ni][r];
                if constexpr (MODE == 0) {
                    v += bias[col];
                    u16 hv = f2h(v);
                    if (n0 < 256) {
                        oq[(size_t)row * CI + col] = hv;
                    } else if (n0 < 512) {
                        okk[(size_t)row * CI + (col - 256)] = hv;
                    } else {
                        int d = col - 512;
                        int bi = row >> 12, key = row & (NN - 1);
                        int k5 = key & 31;
                        int skey = (key & ~31) |
                                   ((((k5 >> 2) & 3) << 3) | (k5 & 3) | (((k5 >> 4) & 1) << 2));
                        ov[((size_t)bi * CI + d) * NN + skey] = hv;  // V^T, sigma-permuted
                    }
                } else {
                    size_t o = (size_t)row * 512 + col;
                    of[o] = xres[o] + v + bias[col];
                }
            }
        }
    }
}

// ============ flash attention, swapped-QK^T, 32 q-rows/wave, split-KV x4 ============
// grid 512 = 4 batches x 32 q-tiles(128 rows) x 4 key-splits; block 256 = 4 waves x 32 q-rows
// LDS: Ks 2x[32][256] swz (32KB dbuf) | Vt 2x[256][32] swz (32KB dbuf) = 65536 B
#define KVB 32
#define NSPLIT 4
#define KEYS_PER (NN / NSPLIT)          // 1024
#define NTILE (KEYS_PER / KVB)          // 32
#define ATTN_LDS 65536

__global__ __launch_bounds__(256, 2) void attn_kernel(
    const u16* __restrict__ Qg, const u16* __restrict__ Kg,
    const u16* __restrict__ Vtg, u16* __restrict__ po01, u16* __restrict__ po23,
    float* __restrict__ ml) {
    extern __shared__ u16 smem[];

    const int tid = threadIdx.x, lane = tid & 63, wv = tid >> 6;
    const int l15 = lane & 15, kg = lane >> 4;
    // XCD-aware swizzle (512 % 8 == 0)
    const int sid = (blockIdx.x & 7) * 64 + (blockIdx.x >> 3);
    const int qt = sid & 31;
    const int b = (sid >> 5) & 3;
    const int sp = sid >> 7;             // key split 0..3
    const int kvoff = sp * KEYS_PER;
    const size_t kvbase = (size_t)b * NN * CI;
    const size_t vbase = (size_t)b * CI * NN;

    // Q as B-fragments: lane holds Q rows (l15, l15+16), d-slice kg*8+j at step kk
    f16x8 qf[2][8];
    {
        const u16* qp0 = Qg + ((size_t)b * NN + qt * 128 + wv * 32 + l15) * CI + kg * 8;
        #pragma unroll
        for (int qs = 0; qs < 2; qs++)
            #pragma unroll
            for (int kk = 0; kk < 8; kk++)
                qf[qs][kk] = *(const f16x8*)(qp0 + (size_t)qs * 16 * CI + kk * 32);
    }

    // acc: O[q][d], col d = dt*16+l15, row q = qs*16 + kg*4 + r
    f32x4 acc[16][2];
    #pragma unroll
    for (int i = 0; i < 16; i++)
        #pragma unroll
        for (int qs = 0; qs < 2; qs++) acc[i][qs] = (f32x4){0.f, 0.f, 0.f, 0.f};
    float mrow[2] = {-1e30f, -1e30f}, lrow[2] = {0.f, 0.f};

    // ---- hoisted staging geometry ----
    const int chunk = tid & 31, rb = tid >> 5;       // K staging
    const u16* ksrc[4];
    int kdst[4];
    #pragma unroll
    for (int i = 0; i < 4; i++) {
        int row = i * 8 + rb;
        int sc = chunk ^ (row & 7);
        ksrc[i] = Kg + kvbase + (size_t)(kvoff + KVB + row) * CI + sc * 8;  // tile 1
        kdst[i] = row * 256 + chunk * 8;
    }
    const int vc = tid & 3, vdb = tid >> 2;          // V staging
    const u16* vsrc[4];
    int vdst[4];
    #pragma unroll
    for (int i = 0; i < 4; i++) {
        int d = i * 64 + vdb;
        int sc = vc ^ ((d >> 1) & 3);
        vsrc[i] = Vtg + vbase + (size_t)d * NN + kvoff + KVB + sc * 8;     // tile 1
        vdst[i] = d * KVB + vc * 8;
    }

    // prologue: stage tile 0 into buffer 0
    #pragma unroll
    for (int i = 0; i < 4; i++) {
        int row = i * 8 + rb;
        int sc = chunk ^ (row & 7);
        gload16(Kg + kvbase + (size_t)(kvoff + row) * CI + sc * 8, smem + kdst[i]);
    }
    #pragma unroll
    for (int i = 0; i < 4; i++) {
        int d = i * 64 + vdb;
        int sc = vc ^ ((d >> 1) & 3);
        gload16(Vtg + vbase + (size_t)d * NN + kvoff + sc * 8, smem + 16384 + vdst[i]);
    }
    __syncthreads();

    for (int it = 0; it < NTILE; ++it) {
        const int cur = (it & 1) * 8192;
        const u16* Ks = smem + cur;
        const u16* Vt = smem + 16384 + cur;
        if (it + 1 < NTILE) {
            const int nxt = cur ^ 8192;
            #pragma unroll
            for (int i = 0; i < 4; i++) {
                gload16(ksrc[i], smem + nxt + kdst[i]);
                ksrc[i] += KVB * CI;
            }
            #pragma unroll
            for (int i = 0; i < 4; i++) {
                gload16(vsrc[i], smem + 16384 + nxt + vdst[i]);
                vsrc[i] += KVB;
            }
        }

        // ---- S^T = K Q^T : lane holds S[key = nt*16+kg*4+r][q = l15+16qs]
        f32x4 s[2][2];
        #pragma unroll
        for (int qs = 0; qs < 2; qs++)
            #pragma unroll
            for (int nt = 0; nt < 2; nt++) s[qs][nt] = (f32x4){0.f, 0.f, 0.f, 0.f};
        __builtin_amdgcn_s_setprio(1);
        #pragma unroll
        for (int kk = 0; kk < 8; kk++) {
            #pragma unroll
            for (int nt = 0; nt < 2; nt++) {
                int krow = nt * 16 + l15;
                f16x8 kf = *(const f16x8*)&Ks[krow * 256 + (((kk * 4 + kg) ^ (krow & 7)) << 3)];
                s[0][nt] = mfma16(kf, qf[0][kk], s[0][nt]);
                s[1][nt] = mfma16(kf, qf[1][kk], s[1][nt]);
            }
        }
        __builtin_amdgcn_s_setprio(0);

        // ---- softmax, lane-local rows (q = l15+16qs) + 2-shfl cross-kg reduce
        float mx[2];
        #pragma unroll
        for (int qs = 0; qs < 2; qs++) {
            float m8 = fmaxf(fmaxf(fmaxf(s[qs][0][0], s[qs][0][1]), fmaxf(s[qs][0][2], s[qs][0][3])),
                             fmaxf(fmaxf(s[qs][1][0], s[qs][1][1]), fmaxf(s[qs][1][2], s[qs][1][3])));
            m8 = fmaxf(m8, __shfl_xor(m8, 16));
            m8 = fmaxf(m8, __shfl_xor(m8, 32));
            mx[qs] = m8;
        }
        float need = fmaxf(mx[0] - mrow[0], mx[1] - mrow[1]);
        if (!__all(need <= 8.f)) {   // defer-max: rescale only when needed
            float sclv[2];
            #pragma unroll
            for (int qs = 0; qs < 2; qs++) {
                float mnew = fmaxf(mrow[qs], mx[qs]);
                sclv[qs] = __expf(mrow[qs] - mnew);
                lrow[qs] *= sclv[qs];
                mrow[qs] = mnew;
            }
            #pragma unroll
            for (int qs = 0; qs < 2; qs++)
                #pragma unroll
                for (int r = 0; r < 4; r++) {
                    float sr = __shfl(sclv[qs], (lane & 48) | (kg * 4 + r), 64);
                    #pragma unroll
                    for (int dt = 0; dt < 16; dt++) acc[dt][qs][r] *= sr;
                }
        }
        // exp + row-sum + pack P to fp16 A-fragment (keys at mfma-k = kg*8 + nt*4 + r)
        f16x8 pa[2];
        #pragma unroll
        for (int qs = 0; qs < 2; qs++) {
            float rs = 0.f;
            #pragma unroll
            for (int nt = 0; nt < 2; nt++)
                #pragma unroll
                for (int r = 0; r < 4; r++) {
                    float p = __expf(s[qs][nt][r] - mrow[qs]);
                    rs += p;
                    pa[qs][nt * 4 + r] = (_Float16)p;
                }
            rs += __shfl_xor(rs, 16);
            rs += __shfl_xor(rs, 32);
            lrow[qs] += rs;
        }

        // ---- PV: O[q][d] += P(32q x 32k) * V(32k x 256d)
        __builtin_amdgcn_s_setprio(1);
        #pragma unroll
        for (int dt = 0; dt < 16; dt++) {
            int d = dt * 16 + l15;
            f16x8 vf = *(const f16x8*)&Vt[d * KVB + ((kg ^ ((l15 >> 1) & 3)) << 3)];
            acc[dt][0] = mfma16(pa[0], vf, acc[dt][0]);
            acc[dt][1] = mfma16(pa[1], vf, acc[dt][1]);
        }
        __builtin_amdgcn_s_setprio(0);

        __syncthreads();  // waves done with cur buffers; prefetch drained
    }

    // ---- write normalized partial O (fp16) + m/l
    const int row0 = b * NN + qt * 128 + wv * 32;
    u16* pod = (sp < 2) ? (po01 + (size_t)sp * RR * CI)
                        : (po23 + (size_t)(sp - 2) * RR * CI);
    #pragma unroll
    for (int qs = 0; qs < 2; qs++)
        #pragma unroll
        for (int r = 0; r < 4; r++) {
            float li = __shfl(lrow[qs], (lane & 48) | (kg * 4 + r), 64);
            float inv = 1.f / li;
            int row = row0 + qs * 16 + kg * 4 + r;
            #pragma unroll
            for (int dt = 0; dt < 16; dt++)
                pod[(size_t)row * CI + dt * 16 + l15] = f2h(acc[dt][qs][r] * inv);
        }
    if (kg == 0) {
        #pragma unroll
        for (int qs = 0; qs < 2; qs++) {
            int row = row0 + qs * 16 + l15;
            ml[row * 8 + sp * 2] = mrow[qs];
            ml[row * 8 + sp * 2 + 1] = lrow[qs];
        }
    }
}

// ============ combine the four KV-splits ============
__global__ void attn_combine(const u16* __restrict__ po01, const u16* __restrict__ po23,
                             const float* __restrict__ ml, u16* __restrict__ yb) {
    const int gid = blockIdx.x * 256 + threadIdx.x;  // RR*CI/4 threads
    const int row = gid >> 6;
    const int d0 = (gid & 63) * 4;
    f32x4 ml0 = ((const f32x4*)ml)[row * 2];
    f32x4 ml1 = ((const f32x4*)ml)[row * 2 + 1];
    float m = fmaxf(fmaxf(ml0[0], ml0[2]), fmaxf(ml1[0], ml1[2]));
    float c0 = __expf(ml0[0] - m) * ml0[1];
    float c1 = __expf(ml0[2] - m) * ml0[3];
    float c2 = __expf(ml1[0] - m) * ml1[1];
    float c3 = __expf(ml1[2] - m) * ml1[3];
    float inv = 1.f / (c0 + c1 + c2 + c3);
    const size_t off = (size_t)row * CI + d0;
    const size_t spstride = (size_t)RR * CI;
    u16x4 p0 = *(const u16x4*)(po01 + off);
    u16x4 p1 = *(const u16x4*)(po01 + spstride + off);
    u16x4 p2 = *(const u16x4*)(po23 + off);
    u16x4 p3 = *(const u16x4*)(po23 + spstride + off);
    u16x4 o;
    #pragma unroll
    for (int e = 0; e < 4; e++)
        o[e] = f2h((c0 * h2f(p0[e]) + c1 * h2f(p1[e]) +
                    c2 * h2f(p2[e]) + c3 * h2f(p3[e])) * inv);
    *(u16x4*)(yb + off) = o;
}

// ============ launcher ============
extern "C" void kernel_launch(void* const* d_in, const int* in_sizes, int n_in,
                              void* d_out, int out_size, void* d_ws, size_t ws_size,
                              hipStream_t stream) {
    (void)in_sizes; (void)n_in; (void)out_size; (void)ws_size;
    const float* x     = (const float*)d_in[0];
    const float* gamma = (const float*)d_in[1];
    const float* beta  = (const float*)d_in[2];
    const float* thw   = (const float*)d_in[3];
    const float* thb   = (const float*)d_in[4];
    const float* phw   = (const float*)d_in[5];
    const float* phb   = (const float*)d_in[6];
    const float* gw    = (const float*)d_in[7];
    const float* gb    = (const float*)d_in[8];
    const float* ww    = (const float*)d_in[9];
    const float* wb    = (const float*)d_in[10];

    char* ws = (char*)d_ws;
    u16* po01  = (u16*)(ws + OFF_FEAT);   // attn partial O splits 0,1 (16MB)
    u16* qb    = (u16*)(ws + OFF_Q);
    u16* kb    = (u16*)(ws + OFF_K);
    u16* vtb   = (u16*)(ws + OFF_V);
    u16* yb    = (u16*)(ws + OFF_Y);
    u16* wqkv  = (u16*)(ws + OFF_WQKV);
    u16* wo    = (u16*)(ws + OFF_WO);
    float* bqkv = (float*)(ws + OFF_BQKV);
    float* part = (float*)(ws + OFF_PART); // reused: attn m/l (512KB exactly)
    float* ss   = (float*)(ws + OFF_SS);
    float* out  = (float*)d_out;
    u16* po23  = (u16*)d_out;             // scratch: first 16MB of d_out = splits 2,3

    (void)hipFuncSetAttribute((const void*)attn_kernel,
                              hipFuncAttributeMaxDynamicSharedMemorySize, ATTN_LDS);

    bn_partial<<<128, 512, 0, stream>>>(x, part);
    prep_kernel<<<1025, 512, 0, stream>>>(part, gamma, beta, ss,
                                          thw, phw, gw, thb, phb, gb, ww, wqkv, wo, bqkv);
    gemm_bt<0><<<dim3(128, 6), 256, 0, stream>>>(nullptr, x, ss, wqkv, 512, bqkv, nullptr,
                                                 qb, kb, vtb, nullptr);
    attn_kernel<<<512, 256, ATTN_LDS, stream>>>(qb, kb, vtb, po01, po23, part);
    attn_combine<<<RR * CI / 4 / 256, 256, 0, stream>>>(po01, po23, part, yb);
    gemm_bt<1><<<dim3(128, 4), 256, 0, stream>>>(yb, nullptr, nullptr, wo, 256, wb, x,
                                                 nullptr, nullptr, nullptr, out);
}